// Round 14
// baseline (1252.846 us; speedup 1.0000x reference)
//
#include <hip/hip_runtime.h>

// PopNet R9 (6th submit; 5 infra failures): split into compute + expander.
// A (popnet_compute): exact R8 math, but emits per-thread spike BITMASKS to d_ws
//   ([25][B] uint64, wave-contiguous), spk2 direct (wave-contiguous 12B/thread),
//   x_pop epilogue via LDS idxs. NO in-loop barriers, NO per-step LDS.
// B (spk1_expand): pure grid-stride expander, masks -> 839MB spk1 stream,
//   structurally identical to fillBuffer (which measures 6.25 TB/s).
// Diagnostic: if B runs at fill rate, total ~800us; if B caps at the fused
// kernel's 2.8 TB/s, the store path is the ceiling.

#define BINS   15
#define STEPS  25
#define NH     64
#define NO     3
#define NF     4
#define TPB    256

typedef float f32x4 __attribute__((ext_vector_type(4)));

__global__ __launch_bounds__(TPB, 2) void popnet_compute(
                              const float* __restrict__ x,
                              const float* __restrict__ W1,
                              const float* __restrict__ b1,
                              const float* __restrict__ W2,
                              const float* __restrict__ b2,
                              float* __restrict__ out,
                              unsigned long long* __restrict__ masks, int B)
{
    __shared__ float W1s[NH * 60];
    __shared__ float b1s[NH];
    __shared__ float W2s[NO * NH];
    __shared__ float b2s[NO];
    __shared__ unsigned int idxs[TPB];

    const int tid = threadIdx.x;
    for (int i = tid; i < NH * 60; i += TPB) W1s[i] = W1[i];
    for (int i = tid; i < NH;      i += TPB) b1s[i] = b1[i];
    for (int i = tid; i < NO * NH; i += TPB) W2s[i] = W2[i];
    if (tid < NO) b2s[tid] = b2[tid];
    __syncthreads();

    const int blockStart = blockIdx.x * TPB;
    const int b = blockStart + tid;

    // ---- population encode ----
    const f32x4 xv = *reinterpret_cast<const f32x4*>(x + (size_t)b * NF);
    int idx[NF];
#pragma unroll
    for (int f = 0; f < NF; ++f) {
        float v = fminf(fmaxf(xv[f], 0.0f), 1.0f);
        int id = (int)(v * 14.0f);
        id = min(max(id, 0), BINS - 1);
        idx[f] = id;
    }
    idxs[tid] = (unsigned)idx[0] | ((unsigned)idx[1] << 4) |
                ((unsigned)idx[2] << 8) | ((unsigned)idx[3] << 12);
    const int c0 = idx[0], c1 = 15 + idx[1], c2 = 30 + idx[2], c3 = 45 + idx[3];

    // ---- cur1 (ascending adds, bias last — matches np bit-exactly, absmax 0.0) ----
    float cur1[NH];
#pragma unroll
    for (int o = 0; o < NH; ++o) {
        const float* row = W1s + o * 60;
        float s = __fadd_rn(__fadd_rn(__fadd_rn(row[c0], row[c1]), row[c2]), row[c3]);
        cur1[o] = __fadd_rn(s, b1s[o]);
    }

    float mem1[NH];
#pragma unroll
    for (int o = 0; o < NH; ++o) mem1[o] = 0.0f;
    float mem2[NO] = {0.0f, 0.0f, 0.0f};

    const size_t off2x = (size_t)STEPS * B * NO + (size_t)STEPS * B * NH;  // x_pop
    float* const out_spk2 = out;
    float* const out_xpop = out + off2x;

#pragma unroll 1
    for (int t = 0; t < STEPS; ++t) {
        float acc0 = 0.0f, acc1 = 0.0f, acc2 = 0.0f;
        unsigned long long bits = 0ull;
#pragma unroll
        for (int n = 0; n < NH; ++n) {
            float m = mem1[n];
            const float reset = (m > 1.0f) ? 1.0f : 0.0f;
            m = __fsub_rn(__fadd_rn(__fmul_rn(0.8f, m), cur1[n]), reset);
            mem1[n] = m;
            const bool fire = (m > 1.0f);
            bits |= ((unsigned long long)(fire ? 1u : 0u)) << n;
            acc0 = __fadd_rn(acc0, fire ? W2s[0 * NH + n] : 0.0f);
            acc1 = __fadd_rn(acc1, fire ? W2s[1 * NH + n] : 0.0f);
            acc2 = __fadd_rn(acc2, fire ? W2s[2 * NH + n] : 0.0f);
        }
        masks[(size_t)t * B + b] = bits;            // 8B/thread, wave-contiguous

        const float cu[NO] = {__fadd_rn(acc0, b2s[0]), __fadd_rn(acc1, b2s[1]), __fadd_rn(acc2, b2s[2])};
        float* const w2dst = out_spk2 + ((size_t)t * B + b) * NO;
#pragma unroll
        for (int k = 0; k < NO; ++k) {
            float m = mem2[k];
            const float reset = (m > 1.0f) ? 1.0f : 0.0f;
            m = __fsub_rn(__fadd_rn(__fmul_rn(0.8f, m), cu[k]), reset);
            mem2[k] = m;
            w2dst[k] = (m > 1.0f) ? 1.0f : 0.0f;    // 12B/thread, wave-contiguous
        }
    }

    __syncthreads();   // idxs[] visible for cooperative x_pop expansion

    // ---- x_pop one-hot: TPB*60 floats = 3840 float4, 15 per thread ----
    float* const basex = out_xpop + (size_t)blockStart * 60;
#pragma unroll
    for (int i = 0; i < 15; ++i) {
        const int g = tid + i * TPB;
        const int bb = g / 15;
        const int r = g - bb * 15;
        const unsigned pk = idxs[bb];
        const int j0 = r * 4;
        f32x4 v;
#pragma unroll
        for (int k = 0; k < 4; ++k) {
            const int j = j0 + k;
            const int feat = j / 15;
            const int bin = j - feat * 15;
            v[k] = (bin == (int)((pk >> (feat * 4)) & 15u)) ? 1.0f : 0.0f;
        }
        reinterpret_cast<f32x4*>(basex)[g] = v;
    }
}

// Pure streaming expander: one float4 (4 neurons) per thread-iteration.
__global__ __launch_bounds__(TPB) void spk1_expand(
                              const unsigned long long* __restrict__ masks,
                              float* __restrict__ out_spk1, int B)
{
    const long long total = (long long)STEPS * B * 16;   // float4 count
    const int per_shift = 31 - __clz(B * 16);            // B is a power of two
    const long long stride = (long long)gridDim.x * TPB;
    f32x4* const dst = reinterpret_cast<f32x4*>(out_spk1);

    for (long long g = (long long)blockIdx.x * TPB + threadIdx.x; g < total; g += stride) {
        const int t = (int)(g >> per_shift);
        const int r = (int)(g & ((1ll << per_shift) - 1));
        const int b = r >> 4;
        const int q = r & 15;
        const unsigned long long w = masks[(size_t)t * B + b];  // 16-lane broadcast
        const int n0 = q * 4;
        f32x4 v;
        v.x = (float)((w >> (n0 + 0)) & 1ull);
        v.y = (float)((w >> (n0 + 1)) & 1ull);
        v.z = (float)((w >> (n0 + 2)) & 1ull);
        v.w = (float)((w >> (n0 + 3)) & 1ull);
        dst[g] = v;
    }
}

extern "C" void kernel_launch(void* const* d_in, const int* in_sizes, int n_in,
                              void* d_out, int out_size, void* d_ws, size_t ws_size,
                              hipStream_t stream) {
    const float* x  = (const float*)d_in[0];
    const float* W1 = (const float*)d_in[1];
    const float* b1 = (const float*)d_in[2];
    const float* W2 = (const float*)d_in[3];
    const float* b2 = (const float*)d_in[4];
    float* out = (float*)d_out;
    unsigned long long* masks = (unsigned long long*)d_ws;
    const int B = in_sizes[0] / NF;

    popnet_compute<<<B / TPB, TPB, 0, stream>>>(x, W1, b1, W2, b2, out, masks, B);

    float* out_spk1 = out + (size_t)STEPS * B * NO;
    spk1_expand<<<2048, TPB, 0, stream>>>(masks, out_spk1, B);
}

// Round 15
// 990.058 us; speedup vs baseline: 1.2654x; 1.2654x over previous
//
#include <hip/hip_runtime.h>

// PopNet R15: 4 threads per element (16 neurons each). R14 showed the compute
// phase alone is ~425-525us at 8 waves/CU (1 thr/elem) — latency-starved, not
// store-bound. This quadruples waves (8192 = up to 32/CU), holds W2 in regs
// (no in-loop LDS), keeps the EXACT ascending cur2 fold via 4-phase lane
// handoff (+0.0 adds exact; shfl broadcasts prefix), stores spk1 direct.
// Bit-exact vs R1-R8 lineage (absmax 0.0).

#define BINS   15
#define STEPS  25
#define NH     64
#define NO     3
#define NF     4
#define TPB    256
#define EPB    (TPB / 4)   // 64 elements per block

typedef float f32x4 __attribute__((ext_vector_type(4)));

__global__ __launch_bounds__(TPB, 4) void popnet_kernel(
                              const float* __restrict__ x,
                              const float* __restrict__ W1,
                              const float* __restrict__ b1,
                              const float* __restrict__ W2,
                              const float* __restrict__ b2,
                              float* __restrict__ out, int B)
{
    __shared__ float W1s[NH * 60];
    __shared__ float b1s[NH];
    __shared__ float W2s[NO * NH];
    __shared__ float b2s[NO];
    __shared__ unsigned int idxs[EPB];

    const int tid = threadIdx.x;
    for (int i = tid; i < NH * 60; i += TPB) W1s[i] = W1[i];
    for (int i = tid; i < NH;      i += TPB) b1s[i] = b1[i];
    for (int i = tid; i < NO * NH; i += TPB) W2s[i] = W2[i];
    if (tid < NO) b2s[tid] = b2[tid];
    __syncthreads();

    const int lane   = tid & 63;
    const int q      = tid & 3;            // sub-lane within element (owns neurons q*16..q*16+15)
    const int eLocal = tid >> 2;           // element within block
    const int e      = blockIdx.x * EPB + eLocal;
    const int lbase  = lane & ~3;          // wave-lane of sub-lane 0 of this element

    // ---- population encode: lane q computes idx of feature q (coalesced: addr = global tid) ----
    const float xq = x[(size_t)e * NF + q];
    float v = fminf(fmaxf(xq, 0.0f), 1.0f);
    int myid = (int)(v * 14.0f);           // float mul then trunc — matches np
    myid = min(max(myid, 0), BINS - 1);

    int idx_f[NF];
#pragma unroll
    for (int f = 0; f < NF; ++f) idx_f[f] = __shfl(myid, lbase + f);
    const int c0 = idx_f[0], c1 = 15 + idx_f[1], c2 = 30 + idx_f[2], c3 = 45 + idx_f[3];
    if (q == 0)
        idxs[eLocal] = (unsigned)idx_f[0] | ((unsigned)idx_f[1] << 4) |
                       ((unsigned)idx_f[2] << 8) | ((unsigned)idx_f[3] << 12);

    // ---- per-thread constants: W2 columns + cur1 (ascending adds, bias last) ----
    const int n0 = q * 16;
    float w2r0[16], w2r1[16], w2r2[16], cur1[16], mem1[16];
#pragma unroll
    for (int j = 0; j < 16; ++j) {
        const int n = n0 + j;
        w2r0[j] = W2s[0 * NH + n];
        w2r1[j] = W2s[1 * NH + n];
        w2r2[j] = W2s[2 * NH + n];
        const float* row = W1s + n * 60;
        float s = __fadd_rn(__fadd_rn(__fadd_rn(row[c0], row[c1]), row[c2]), row[c3]);
        cur1[j] = __fadd_rn(s, b1s[n]);
        mem1[j] = 0.0f;
    }
    float mem2[NO] = {0.0f, 0.0f, 0.0f};

    float* const out_spk2 = out;
    float* const out_spk1 = out + (size_t)STEPS * B * NO;
    float* const out_xpop = out + (size_t)STEPS * B * NO + (size_t)STEPS * B * NH;

#pragma unroll 1
    for (int t = 0; t < STEPS; ++t) {
        // ---- LIF layer 1 for my 16 neurons ----
        float sp[16];
#pragma unroll
        for (int j = 0; j < 16; ++j) {
            float m = mem1[j];
            const float reset = (m > 1.0f) ? 1.0f : 0.0f;
            m = __fsub_rn(__fadd_rn(__fmul_rn(0.8f, m), cur1[j]), reset);
            mem1[j] = m;
            sp[j] = (m > 1.0f) ? 1.0f : 0.0f;
        }

        // ---- spk1 store: 4 float4 per thread (4 back-to-back instrs fill 4KB span densely) ----
        float* const dst = out_spk1 + ((size_t)t * B + e) * NH + n0;
#pragma unroll
        for (int j4 = 0; j4 < 4; ++j4) {
            f32x4 vv;
            vv.x = sp[j4 * 4 + 0];
            vv.y = sp[j4 * 4 + 1];
            vv.z = sp[j4 * 4 + 2];
            vv.w = sp[j4 * 4 + 3];
            reinterpret_cast<f32x4*>(dst)[j4] = vv;
        }

        // ---- cur2: exact ascending fold, 4-phase lane handoff ----
        // phase p: only sub-lane p adds its 16 terms (others add +0.0 — exact);
        // shfl then broadcasts the true prefix to all 4 lanes.
        float a0 = 0.0f, a1 = 0.0f, a2 = 0.0f;
#pragma unroll
        for (int p = 0; p < 4; ++p) {
            const bool mine = (q == p);
#pragma unroll
            for (int j = 0; j < 16; ++j) {
                const bool on = mine && (sp[j] != 0.0f);
                a0 = __fadd_rn(a0, on ? w2r0[j] : 0.0f);
                a1 = __fadd_rn(a1, on ? w2r1[j] : 0.0f);
                a2 = __fadd_rn(a2, on ? w2r2[j] : 0.0f);
            }
            a0 = __shfl(a0, lbase + p);
            a1 = __shfl(a1, lbase + p);
            a2 = __shfl(a2, lbase + p);
        }

        // ---- LIF layer 2 (replicated on all 4 lanes; uniform) ----
        const float cu[NO] = {__fadd_rn(a0, b2s[0]), __fadd_rn(a1, b2s[1]), __fadd_rn(a2, b2s[2])};
        float s2[NO];
#pragma unroll
        for (int k = 0; k < NO; ++k) {
            float m = mem2[k];
            const float reset = (m > 1.0f) ? 1.0f : 0.0f;
            m = __fsub_rn(__fadd_rn(__fmul_rn(0.8f, m), cu[k]), reset);
            mem2[k] = m;
            s2[k] = (m > 1.0f) ? 1.0f : 0.0f;
        }
        if (q < NO) {
            const float mys2 = (q == 0) ? s2[0] : (q == 1) ? s2[1] : s2[2];
            out_spk2[((size_t)t * B + e) * NO + q] = mys2;
        }
    }

    __syncthreads();   // idxs[] (written pre-loop) visible for cooperative x_pop

    // ---- x_pop one-hot: EPB*60 floats = 960 float4 per block ----
    float* const basex = out_xpop + (size_t)(blockIdx.x * EPB) * 60;
#pragma unroll
    for (int i = 0; i < 4; ++i) {
        const int g = tid + i * TPB;          // [0,1024), need <960
        if (g < 960) {
            const int el = g / 15;
            const int r  = g - el * 15;
            const unsigned pk = idxs[el];
            const int j0 = r * 4;
            f32x4 vv;
#pragma unroll
            for (int k = 0; k < 4; ++k) {
                const int j = j0 + k;
                const int feat = j / 15;
                const int bin  = j - feat * 15;
                vv[k] = (bin == (int)((pk >> (feat * 4)) & 15u)) ? 1.0f : 0.0f;
            }
            reinterpret_cast<f32x4*>(basex)[g] = vv;
        }
    }
}

extern "C" void kernel_launch(void* const* d_in, const int* in_sizes, int n_in,
                              void* d_out, int out_size, void* d_ws, size_t ws_size,
                              hipStream_t stream) {
    const float* x  = (const float*)d_in[0];
    const float* W1 = (const float*)d_in[1];
    const float* b1 = (const float*)d_in[2];
    const float* W2 = (const float*)d_in[3];
    const float* b2 = (const float*)d_in[4];
    float* out = (float*)d_out;
    const int B = in_sizes[0] / NF;
    popnet_kernel<<<B / EPB, TPB, 0, stream>>>(x, W1, b1, W2, b2, out, B);
}